// Round 1
// baseline (151.889 us; speedup 1.0000x reference)
//
#include <hip/hip_runtime.h>
#include <hip/hip_bf16.h>

// GaussianCodebook: out[b,s,c] = mean_d((x[b,s,d]-cb[d,c])^2)
//                 = x2[m] + c2[n] - (2/D) * dot(x[m,:], cb[:,n])
// B=8 S=4096 D=512 C=2048  -> GEMM M=32768 N=2048 K=512 (bf16 MFMA) + epilogue.

typedef __attribute__((ext_vector_type(8))) short bf16x8;
typedef __attribute__((ext_vector_type(4))) float f32x4;

#define M_ROWS 32768
#define K_DIM  512
#define N_COLS 2048

__device__ __forceinline__ unsigned short f2bf(float f) {
    unsigned int u = __float_as_uint(f);
    return (unsigned short)((u + 0x7fffu + ((u >> 16) & 1u)) >> 16);  // RNE
}

__device__ __forceinline__ void gload_lds16(const void* g, void* l) {
    __builtin_amdgcn_global_load_lds(
        (const __attribute__((address_space(1))) unsigned int*)g,
        (__attribute__((address_space(3))) unsigned int*)l,
        16, 0, 0);
}

// ---- prep_x: cast x f32 -> bf16, and x2[m] = mean_d x^2 ----
// one wave per row of 512; lane covers float4 #lane and #(lane+64)
__global__ __launch_bounds__(256) void prep_x_kernel(const float* __restrict__ x,
                                                     unsigned short* __restrict__ xb,
                                                     float* __restrict__ x2) {
    const int wid = threadIdx.x >> 6;
    const int lane = threadIdx.x & 63;
    const int row = (blockIdx.x << 2) + wid;
    const float4* p4 = reinterpret_cast<const float4*>(x + (size_t)row * K_DIM);
    float4 v0 = p4[lane];
    float4 v1 = p4[lane + 64];
    float ss = v0.x*v0.x + v0.y*v0.y + v0.z*v0.z + v0.w*v0.w
             + v1.x*v1.x + v1.y*v1.y + v1.z*v1.z + v1.w*v1.w;
    union { unsigned short us[4]; uint2 u2; } pa, pb;
    pa.us[0] = f2bf(v0.x); pa.us[1] = f2bf(v0.y); pa.us[2] = f2bf(v0.z); pa.us[3] = f2bf(v0.w);
    pb.us[0] = f2bf(v1.x); pb.us[1] = f2bf(v1.y); pb.us[2] = f2bf(v1.z); pb.us[3] = f2bf(v1.w);
    uint2* dst = reinterpret_cast<uint2*>(xb + (size_t)row * K_DIM);
    dst[lane]      = pa.u2;
    dst[lane + 64] = pb.u2;
    #pragma unroll
    for (int off = 32; off; off >>= 1) ss += __shfl_xor(ss, off);
    if (lane == 0) x2[row] = ss * (1.0f / (float)K_DIM);
}

// ---- prep_cb: transpose cb [K=512][N=2048] f32 -> cbT [N][K] bf16, scaled by 2/D = 2^-8 ----
__global__ __launch_bounds__(256) void prep_cb_kernel(const float* __restrict__ cb,
                                                      unsigned short* __restrict__ cbT) {
    __shared__ float tile[32][65];
    const int k0 = blockIdx.x * 32;
    const int n0 = blockIdx.y * 64;
    const int tx = threadIdx.x & 63;
    const int ty = threadIdx.x >> 6;
    #pragma unroll
    for (int i = 0; i < 8; ++i) {
        const int k = ty + i * 4;
        tile[k][tx] = cb[(size_t)(k0 + k) * N_COLS + n0 + tx];
    }
    __syncthreads();
    const int kc = threadIdx.x & 31;
    const int nr = threadIdx.x >> 5;
    #pragma unroll
    for (int i = 0; i < 8; ++i) {
        const int n = nr + i * 8;
        cbT[(size_t)(n0 + n) * K_DIM + k0 + kc] = f2bf(tile[kc][n] * 0.00390625f);
    }
}

// ---- c2[n] = mean_k cb[k][n]^2 (deterministic two-stage, no atomics) ----
__global__ __launch_bounds__(256) void c2_kernel(const float* __restrict__ cb,
                                                 float* __restrict__ c2) {
    __shared__ float p[4][64];
    const int t = threadIdx.x;
    const int nl = t & 63;
    const int kc = t >> 6;
    const int n = blockIdx.x * 64 + nl;
    float s = 0.0f;
    for (int k = kc * 128; k < kc * 128 + 128; ++k) {
        float v = cb[(size_t)k * N_COLS + n];
        s += v * v;
    }
    p[kc][nl] = s;
    __syncthreads();
    if (t < 64) {
        c2[blockIdx.x * 64 + t] =
            (p[0][t] + p[1][t] + p[2][t] + p[3][t]) * (1.0f / (float)K_DIM);
    }
}

// ---- GEMM: out[m][n] = x2[m] + c2[n] - sum_k A[m][k]*Bt[n][k]  (Bt pre-scaled by 2^-8) ----
// 128x128 tile, BK=32, 256 thr = 4 waves (2x2 of 64x64), 16x16x32 bf16 MFMA,
// global_load_lds width-16 staging (m97 structure).
__global__ __launch_bounds__(256) void gemm_kernel(
        const unsigned short* __restrict__ A,   // [M][K] bf16
        const unsigned short* __restrict__ Bt,  // [N][K] bf16 (scaled)
        const float* __restrict__ x2,
        const float* __restrict__ c2,
        float* __restrict__ out) {
    __shared__ unsigned short As[128 * 32];
    __shared__ unsigned short Bs[128 * 32];
    const int tid  = threadIdx.x;
    const int wid  = tid >> 6;
    const int lane = tid & 63;
    const int wr = wid >> 1, wc = wid & 1;
    const int n0 = blockIdx.x * 128;
    const int m0 = blockIdx.y * 128;
    const int l15 = lane & 15;
    const int lhi = lane >> 4;

    f32x4 acc[4][4] = {};

    const unsigned short* Abase = A  + (size_t)m0 * K_DIM;
    const unsigned short* Bbase = Bt + (size_t)n0 * K_DIM;

    for (int k0 = 0; k0 < K_DIM; k0 += 32) {
        // stage 128x32 bf16 A-tile and B-tile; chunk ch -> row=ch>>2, koff=(ch&3)*8
        #pragma unroll
        for (int r = 0; r < 2; ++r) {
            const int ch  = r * 256 + tid;
            const int row = ch >> 2;
            const int ko  = (ch & 3) * 8;
            // LDS dest must be wave-uniform base; lanes land at base + lane*16
            gload_lds16(Abase + (size_t)row * K_DIM + k0 + ko,
                        &As[(r * 256 + wid * 64) * 8]);
            gload_lds16(Bbase + (size_t)row * K_DIM + k0 + ko,
                        &Bs[(r * 256 + wid * 64) * 8]);
        }
        __syncthreads();   // drains vmcnt (global_load_lds) per barrier semantics

        bf16x8 aF[4], bF[4];
        #pragma unroll
        for (int i = 0; i < 4; ++i) {
            aF[i] = *reinterpret_cast<const bf16x8*>(&As[(wr * 64 + i * 16 + l15) * 32 + lhi * 8]);
            bF[i] = *reinterpret_cast<const bf16x8*>(&Bs[(wc * 64 + i * 16 + l15) * 32 + lhi * 8]);
        }
        #pragma unroll
        for (int i = 0; i < 4; ++i)
            #pragma unroll
            for (int j = 0; j < 4; ++j)
                acc[i][j] = __builtin_amdgcn_mfma_f32_16x16x32_bf16(aF[i], bF[j], acc[i][j], 0, 0, 0);
        __syncthreads();
    }

    // epilogue: C/D layout col = lane&15, row = (lane>>4)*4 + j  [verified m89/m91]
    #pragma unroll
    for (int i = 0; i < 4; ++i) {
        const int mrow = m0 + wr * 64 + i * 16 + lhi * 4;
        const float xv0 = x2[mrow + 0];
        const float xv1 = x2[mrow + 1];
        const float xv2 = x2[mrow + 2];
        const float xv3 = x2[mrow + 3];
        #pragma unroll
        for (int j = 0; j < 4; ++j) {
            const int n = n0 + wc * 64 + j * 16 + l15;
            const float cv = c2[n];
            float* o = out + (size_t)mrow * N_COLS + n;
            o[0 * N_COLS] = xv0 + cv - acc[i][j][0];
            o[1 * N_COLS] = xv1 + cv - acc[i][j][1];
            o[2 * N_COLS] = xv2 + cv - acc[i][j][2];
            o[3 * N_COLS] = xv3 + cv - acc[i][j][3];
        }
    }
}

extern "C" void kernel_launch(void* const* d_in, const int* in_sizes, int n_in,
                              void* d_out, int out_size, void* d_ws, size_t ws_size,
                              hipStream_t stream) {
    const float* x  = (const float*)d_in[0];   // [8,4096,512]
    const float* cb = (const float*)d_in[1];   // [1,1,512,2048]
    float* out = (float*)d_out;                // [8,4096,2048]

    char* ws = (char*)d_ws;
    unsigned short* xb  = (unsigned short*)ws;                               // 32 MB
    unsigned short* cbT = (unsigned short*)(ws + (size_t)33554432);          // 2 MB
    float* x2 = (float*)(ws + (size_t)33554432 + 2097152);                   // 128 KB
    float* c2 = (float*)(ws + (size_t)33554432 + 2097152 + 131072);          // 8 KB

    prep_x_kernel<<<M_ROWS / 4, 256, 0, stream>>>(x, xb, x2);
    prep_cb_kernel<<<dim3(16, 32), 256, 0, stream>>>(cb, cbT);
    c2_kernel<<<N_COLS / 64, 256, 0, stream>>>(cb, c2);
    gemm_kernel<<<dim3(N_COLS / 128, M_ROWS / 128), 256, 0, stream>>>(xb, cbT, x2, c2, out);
}

// Round 2
// 130.716 us; speedup vs baseline: 1.1620x; 1.1620x over previous
//
#include <hip/hip_runtime.h>
#include <hip/hip_bf16.h>

// GaussianCodebook: out[b,s,c] = mean_d((x[b,s,d]-cb[d,c])^2)
//                 = x2[m] + c2[n] - (2/D) * dot(x[m,:], cb[:,n])
// B=8 S=4096 D=512 C=2048  -> GEMM M=32768 N=2048 K=512 (bf16 MFMA) + epilogue.
// R2: 256x256 8-phase counted-vmcnt GEMM (T1 xcd-swizzle, T2 lds-swizzle,
//     T3+T4 8-phase counted vmcnt, T5 setprio). K-split LDS halves so each
//     phase's reads are covered by the vmcnt gates.

typedef __attribute__((ext_vector_type(8))) short bf16x8;
typedef __attribute__((ext_vector_type(4))) float f32x4;

#define M_ROWS 32768
#define K_DIM  512
#define N_COLS 2048
#define NT     8        // K_DIM / 64 K-tiles

__device__ __forceinline__ unsigned short f2bf(float f) {
    unsigned int u = __float_as_uint(f);
    return (unsigned short)((u + 0x7fffu + ((u >> 16) & 1u)) >> 16);  // RNE
}

__device__ __forceinline__ void gload_lds16(const void* g, void* l) {
    __builtin_amdgcn_global_load_lds(
        (const __attribute__((address_space(1))) unsigned int*)g,
        (__attribute__((address_space(3))) unsigned int*)l,
        16, 0, 0);
}

// ---- prep_x: cast x f32 -> bf16, and x2[m] = mean_d x^2 ----
__global__ __launch_bounds__(256) void prep_x_kernel(const float* __restrict__ x,
                                                     unsigned short* __restrict__ xb,
                                                     float* __restrict__ x2) {
    const int wid = threadIdx.x >> 6;
    const int lane = threadIdx.x & 63;
    const int row = (blockIdx.x << 2) + wid;
    const float4* p4 = reinterpret_cast<const float4*>(x + (size_t)row * K_DIM);
    float4 v0 = p4[lane];
    float4 v1 = p4[lane + 64];
    float ss = v0.x*v0.x + v0.y*v0.y + v0.z*v0.z + v0.w*v0.w
             + v1.x*v1.x + v1.y*v1.y + v1.z*v1.z + v1.w*v1.w;
    union { unsigned short us[4]; uint2 u2; } pa, pb;
    pa.us[0] = f2bf(v0.x); pa.us[1] = f2bf(v0.y); pa.us[2] = f2bf(v0.z); pa.us[3] = f2bf(v0.w);
    pb.us[0] = f2bf(v1.x); pb.us[1] = f2bf(v1.y); pb.us[2] = f2bf(v1.z); pb.us[3] = f2bf(v1.w);
    uint2* dst = reinterpret_cast<uint2*>(xb + (size_t)row * K_DIM);
    dst[lane]      = pa.u2;
    dst[lane + 64] = pb.u2;
    #pragma unroll
    for (int off = 32; off; off >>= 1) ss += __shfl_xor(ss, off);
    if (lane == 0) x2[row] = ss * (1.0f / (float)K_DIM);
}

// ---- prep_cb: transpose cb [K=512][N=2048] f32 -> cbT [N][K] bf16, scaled by 2/D = 2^-8 ----
__global__ __launch_bounds__(256) void prep_cb_kernel(const float* __restrict__ cb,
                                                      unsigned short* __restrict__ cbT) {
    __shared__ float tile[32][65];
    const int k0 = blockIdx.x * 32;
    const int n0 = blockIdx.y * 64;
    const int tx = threadIdx.x & 63;
    const int ty = threadIdx.x >> 6;
    #pragma unroll
    for (int i = 0; i < 8; ++i) {
        const int k = ty + i * 4;
        tile[k][tx] = cb[(size_t)(k0 + k) * N_COLS + n0 + tx];
    }
    __syncthreads();
    const int kc = threadIdx.x & 31;
    const int nr = threadIdx.x >> 5;
    #pragma unroll
    for (int i = 0; i < 8; ++i) {
        const int n = nr + i * 8;
        cbT[(size_t)(n0 + n) * K_DIM + k0 + kc] = f2bf(tile[kc][n] * 0.00390625f);
    }
}

// ---- c2[n] = mean_k cb[k][n]^2 ----
__global__ __launch_bounds__(256) void c2_kernel(const float* __restrict__ cb,
                                                 float* __restrict__ c2) {
    __shared__ float p[4][64];
    const int t = threadIdx.x;
    const int nl = t & 63;
    const int kc = t >> 6;
    const int n = blockIdx.x * 64 + nl;
    float s = 0.0f;
    for (int k = kc * 128; k < kc * 128 + 128; ++k) {
        float v = cb[(size_t)k * N_COLS + n];
        s += v * v;
    }
    p[kc][nl] = s;
    __syncthreads();
    if (t < 64) {
        c2[blockIdx.x * 64 + t] =
            (p[0][t] + p[1][t] + p[2][t] + p[3][t]) * (1.0f / (float)K_DIM);
    }
}

// ======================= 256x256 8-phase GEMM =======================
// 512 thr = 8 waves (2M x 4N). Per wave: 128x64 out = 8x4 frags of 16x16.
// LDS: smem[dbuf][half][256*32] bf16, half: 0=A k0..31, 1=A k32..63, 2=B k0..31, 3=B k32..63.
// Swizzle: 16B slot s at row r stored at s ^ ((r>>1)&3)  (involution; write via
// pre-swizzled global source since global_load_lds dest is linear).

__device__ __forceinline__ void stage_half(const unsigned short* __restrict__ gbase,
                                           unsigned short* lbase, int wid, int lane) {
    #pragma unroll
    for (int i = 0; i < 2; ++i) {
        const int o16 = i * 512 + wid * 64 + lane;   // 16B-chunk index within 16KB half
        const int row = o16 >> 2;                    // 64B per row
        const int sl  = (o16 & 3) ^ ((row >> 1) & 3);
        gload_lds16(gbase + (size_t)row * K_DIM + sl * 8,
                    lbase + i * 4096 + wid * 512);
    }
}

__device__ __forceinline__ bf16x8 frag_ld(const unsigned short* h, int r, int lhi) {
    const int off = r * 32 + ((lhi ^ ((r >> 1) & 3)) << 3);
    return *reinterpret_cast<const bf16x8*>(&h[off]);
}

#define BAR()  do { asm volatile("" ::: "memory"); \
                    __builtin_amdgcn_s_barrier();  \
                    asm volatile("" ::: "memory"); } while (0)

__global__ __launch_bounds__(512, 2) void gemm_kernel(
        const unsigned short* __restrict__ A,   // [M][K] bf16
        const unsigned short* __restrict__ Bt,  // [N][K] bf16 (scaled by 2^-8)
        const float* __restrict__ x2,
        const float* __restrict__ c2,
        float* __restrict__ out) {
    __shared__ unsigned short smem[2][4][256 * 32];   // 128 KiB

    const int tid  = threadIdx.x;
    const int wid  = tid >> 6;
    const int lane = tid & 63;
    const int wr = wid >> 2;          // 0..1 -> rows wr*128
    const int wc = wid & 3;           // 0..3 -> cols wc*64
    const int l15 = lane & 15;
    const int lhi = lane >> 4;

    // T1: XCD-bijective swizzle (nwg=1024, 8 XCDs -> 128 consecutive per XCD)
    const int bid  = blockIdx.x;
    const int lbid = (bid & 7) * 128 + (bid >> 3);
    const int m0 = (lbid >> 3) * 256;
    const int n0 = (lbid & 7) * 256;

    const unsigned short* Ab = A  + (size_t)m0 * K_DIM;
    const unsigned short* Bb = Bt + (size_t)n0 * K_DIM;

    f32x4 acc[8][4] = {};

    // prologue: tile 0 (order A0,B0,A1,B1) -> gate A: oldest 4 loads (A0,B0) landed
    stage_half(Ab,      smem[0][0], wid, lane);
    stage_half(Bb,      smem[0][2], wid, lane);
    stage_half(Ab + 32, smem[0][1], wid, lane);
    stage_half(Bb + 32, smem[0][3], wid, lane);
    asm volatile("s_waitcnt vmcnt(4)" ::: "memory");
    BAR();

    for (int t = 0; t < NT; ++t) {
        const int cur = t & 1, nxt = cur ^ 1;
        const unsigned short* hA0 = smem[cur][0];
        const unsigned short* hA1 = smem[cur][1];
        const unsigned short* hB0 = smem[cur][2];
        const unsigned short* hB1 = smem[cur][3];
        const int kn = (t + 1) * 64;
        const bool st = (t < NT - 1);
        bf16x8 a[4], b[4];

        // ---- phase 0: ks=0, M-frags 0-3 ----
        if (st) stage_half(Ab + kn, smem[nxt][0], wid, lane);
        #pragma unroll
        for (int mf = 0; mf < 4; ++mf) a[mf] = frag_ld(hA0, wr * 128 + mf * 16 + l15, lhi);
        #pragma unroll
        for (int nf = 0; nf < 4; ++nf) b[nf] = frag_ld(hB0, wc * 64 + nf * 16 + l15, lhi);
        BAR();
        __builtin_amdgcn_s_setprio(1);
        #pragma unroll
        for (int mf = 0; mf < 4; ++mf)
            #pragma unroll
            for (int nf = 0; nf < 4; ++nf)
                acc[mf][nf] = __builtin_amdgcn_mfma_f32_16x16x32_bf16(a[mf], b[nf], acc[mf][nf], 0, 0, 0);
        __builtin_amdgcn_s_setprio(0);
        BAR();

        // ---- phase 1: ks=0, M-frags 4-7 ----
        if (st) stage_half(Bb + kn, smem[nxt][2], wid, lane);
        #pragma unroll
        for (int mf = 0; mf < 4; ++mf) a[mf] = frag_ld(hA0, wr * 128 + (mf + 4) * 16 + l15, lhi);
        BAR();
        __builtin_amdgcn_s_setprio(1);
        #pragma unroll
        for (int mf = 0; mf < 4; ++mf)
            #pragma unroll
            for (int nf = 0; nf < 4; ++nf)
                acc[mf + 4][nf] = __builtin_amdgcn_mfma_f32_16x16x32_bf16(a[mf], b[nf], acc[mf + 4][nf], 0, 0, 0);
        __builtin_amdgcn_s_setprio(0);
        // gate B: A1,B1 of this tile must land; newer in flight = A0,B0 of t+1 (4) if st
        if (st) asm volatile("s_waitcnt vmcnt(4)" ::: "memory");
        else    asm volatile("s_waitcnt vmcnt(0)" ::: "memory");
        BAR();

        // ---- phase 2: ks=1, M-frags 0-3 ----
        if (st) stage_half(Ab + kn + 32, smem[nxt][1], wid, lane);
        #pragma unroll
        for (int mf = 0; mf < 4; ++mf) a[mf] = frag_ld(hA1, wr * 128 + mf * 16 + l15, lhi);
        #pragma unroll
        for (int nf = 0; nf < 4; ++nf) b[nf] = frag_ld(hB1, wc * 64 + nf * 16 + l15, lhi);
        BAR();
        __builtin_amdgcn_s_setprio(1);
        #pragma unroll
        for (int mf = 0; mf < 4; ++mf)
            #pragma unroll
            for (int nf = 0; nf < 4; ++nf)
                acc[mf][nf] = __builtin_amdgcn_mfma_f32_16x16x32_bf16(a[mf], b[nf], acc[mf][nf], 0, 0, 0);
        __builtin_amdgcn_s_setprio(0);
        BAR();

        // ---- phase 3: ks=1, M-frags 4-7 ----
        if (st) stage_half(Bb + kn + 32, smem[nxt][3], wid, lane);
        #pragma unroll
        for (int mf = 0; mf < 4; ++mf) a[mf] = frag_ld(hA1, wr * 128 + (mf + 4) * 16 + l15, lhi);
        BAR();
        __builtin_amdgcn_s_setprio(1);
        #pragma unroll
        for (int mf = 0; mf < 4; ++mf)
            #pragma unroll
            for (int nf = 0; nf < 4; ++nf)
                acc[mf + 4][nf] = __builtin_amdgcn_mfma_f32_16x16x32_bf16(a[mf], b[nf], acc[mf + 4][nf], 0, 0, 0);
        __builtin_amdgcn_s_setprio(0);
        // gate A for tile t+1: A0,B0(t+1) landed; newer = A1,B1(t+1) (4)
        if (st) asm volatile("s_waitcnt vmcnt(4)" ::: "memory");
        BAR();
    }

    // epilogue: C/D layout col = lane&15, row = (lane>>4)*4 + reg
    #pragma unroll
    for (int mf = 0; mf < 8; ++mf) {
        const int mrow = m0 + wr * 128 + mf * 16 + lhi * 4;
        const float xv0 = x2[mrow + 0];
        const float xv1 = x2[mrow + 1];
        const float xv2 = x2[mrow + 2];
        const float xv3 = x2[mrow + 3];
        #pragma unroll
        for (int nf = 0; nf < 4; ++nf) {
            const int col = n0 + wc * 64 + nf * 16 + l15;
            const float cv = c2[col];
            float* o = out + (size_t)mrow * N_COLS + col;
            o[0 * N_COLS] = xv0 + cv - acc[mf][nf][0];
            o[1 * N_COLS] = xv1 + cv - acc[mf][nf][1];
            o[2 * N_COLS] = xv2 + cv - acc[mf][nf][2];
            o[3 * N_COLS] = xv3 + cv - acc[mf][nf][3];
        }
    }
}

extern "C" void kernel_launch(void* const* d_in, const int* in_sizes, int n_in,
                              void* d_out, int out_size, void* d_ws, size_t ws_size,
                              hipStream_t stream) {
    const float* x  = (const float*)d_in[0];   // [8,4096,512]
    const float* cb = (const float*)d_in[1];   // [1,1,512,2048]
    float* out = (float*)d_out;                // [8,4096,2048]

    char* ws = (char*)d_ws;
    unsigned short* xb  = (unsigned short*)ws;                               // 32 MB
    unsigned short* cbT = (unsigned short*)(ws + (size_t)33554432);          // 2 MB
    float* x2 = (float*)(ws + (size_t)33554432 + 2097152);                   // 128 KB
    float* c2 = (float*)(ws + (size_t)33554432 + 2097152 + 131072);          // 8 KB

    prep_x_kernel<<<M_ROWS / 4, 256, 0, stream>>>(x, xb, x2);
    prep_cb_kernel<<<dim3(16, 32), 256, 0, stream>>>(cb, cbT);
    c2_kernel<<<N_COLS / 64, 256, 0, stream>>>(cb, c2);
    gemm_kernel<<<dim3((M_ROWS / 256) * (N_COLS / 256)), 512, 0, stream>>>(xb, cbT, x2, c2, out);
}